// Round 23
// baseline (268.162 us; speedup 1.0000x reference)
//
#include <hip/hip_runtime.h>
#include <stdint.h>

typedef __bf16 bf16;
typedef __bf16 bf16x4 __attribute__((ext_vector_type(4)));
typedef __bf16 bf16x8 __attribute__((ext_vector_type(8)));
typedef float  f32x4  __attribute__((ext_vector_type(4)));

#define MFMA16(A, B, C) __builtin_amdgcn_mfma_f32_16x16x32_bf16((A), (B), (C), 0, 0, 0)

#define LOG2E 1.4426950408889634f

// B=960 windows, N=144, DIM=192, HEADS=6, hd=32, TYPES=64, n_mask=15
// Softmax: no-max exp2 (logits |L|<~6), log2e prefolded; P unnormalized, O scaled by 1/rsum.
// R8/R21: NEVER cap launch_bounds below live-VGPR need. R10: bias/mask swizzled (worked).
// R11: store-coalescing NEUTRAL. R12/R13/R15-R17: register-stationary W infeasible --
//      allocator remats W from GLOBAL every subtile (the 95us latency wall).
// R14: fragment-order W -> 95us. R20: attn LDS-staged K/V, zeroed pads -> BEST 230.1.
// R23: k_qkv cg-split blocks; W-slice (73.7KB) staged in LDS once -> remat source is
//      now a ~12cy ds_read, not a ~200cy global load. 288 rows/block via 6 double-
//      buffered 48-row x chunks with prefetch-before-compute. LDS 112KB, 1 block/CU.
//
// ws layout (bytes):
//   wqkvt [36][6][64][8] bf16 @ 0        (221184)  (fragment-order, 16x16 strips)
//   woutt [192][192] bf16 @ 221184       (73728)   ends 294912 ([n][k] k-contig)
//   bias_sw [384][20736] bf16 @ 294912   (15925248) ends 16220160
//   obuf  [138240][192] bf16 @ 16220160  (53084160) ends 69304320
//   qb    [960][6][144][32] bf16 @ 69304320  ends 122388480
//   kb    same @ 122388480 ends 175472640
//   vtb   [960][6][32][144] @ 175472640 ends 228556800
//   mask_sw [15][20736] f32 @ 228556800  (1244160) ends 229800960 (~219.2 MiB)

// ---------------- weight transpose + bf16 cast ----------------
__global__ __launch_bounds__(256) void k_prep(const float* __restrict__ wqkv,
                                              const float* __restrict__ wout,
                                              bf16* __restrict__ wqkvt,
                                              bf16* __restrict__ woutt) {
    int i = blockIdx.x * 256 + threadIdx.x;   // 576 blocks
    if (i < 576 * 192) {
        int blk = i >> 9;                     // strip*6 + ks  (0..215)
        int within = i & 511;
        int lane = within >> 3, j = within & 7;
        int strip = blk / 6, ks = blk - strip * 6;
        int col = strip * 16 + (lane & 15);
        int k = ks * 32 + (lane >> 4) * 8 + j;
        wqkvt[i] = (bf16)wqkv[k * 576 + col];
    } else {
        int jj = i - 576 * 192;
        int n = jj / 192, k = jj - n * 192;
        woutt[jj] = (bf16)wout[k * 192 + n];  // [n][k], k-contiguous
    }
}

// ---------------- earth-bias materialization (swizzled, pre-mult log2e) ----------------
__global__ __launch_bounds__(256) void k_bias(const float* __restrict__ btab,
                                              bf16* __restrict__ bias) {
    __shared__ float tb[3312];
    const int th = blockIdx.x;                 // t*6 + h
    for (int i = threadIdx.x; i < 3312; i += 256)
        tb[i] = btab[(size_t)i * 384 + th] * LOG2E;
    __syncthreads();
    bf16* op = bias + (size_t)th * 20736;
    for (int o = threadIdx.x; o < 20736; o += 256) {
        int nt = o / 2304, r1 = o - nt * 2304;
        int ct = r1 / 256,  r2 = r1 - ct * 256;
        int l15 = r2 >> 4,  gr = r2 & 15;
        int n = nt * 16 + l15, m = ct * 16 + gr;
        int zn = n / 72, rn = n - zn * 72, hn = rn / 12, wn = rn - hn * 12;
        int zm = m / 72, rm = m - zm * 72, hm = rm / 12, wm = rm - hm * 12;
        int idx = 828 * (zn + 2 * zm) + 23 * (hn + 6 * hm) + (wn - wm + 11);
        op[o] = (bf16)tb[idx];
    }
}

// ---------------- mask swizzle ----------------
__global__ __launch_bounds__(256) void k_mswz(const float* __restrict__ mask,
                                              float* __restrict__ msw) {
    const int wm = blockIdx.x / 9;
    const int nt = blockIdx.x - wm * 9;
    const int tid = threadIdx.x;
    const int l15 = tid >> 4, gr = tid & 15;
    const float* src = mask + (size_t)wm * 20736 + (size_t)(nt * 16 + l15) * 144 + gr;
    float* dst = msw + (size_t)wm * 20736 + nt * 2304 + tid;
    #pragma unroll
    for (int ct = 0; ct < 9; ++ct)
        dst[ct * 256] = src[ct * 16];
}

// ---------------- QKV projection: W-slice in LDS, cg-split, double-buffered x ----------------
// grid (3, 480): cg = q/k/v group, 288-row chunk. 768 thr = 12 waves; wave w owns
// cols [cg*192 + 16w, +16). W remat source = LDS (cheap), not global (the old wall).
__global__ __launch_bounds__(768, 3) void k_qkv(const float* __restrict__ x,
                                                const float* __restrict__ bqkv,
                                                const bf16* __restrict__ wtf,
                                                bf16* __restrict__ qb,
                                                bf16* __restrict__ kb,
                                                bf16* __restrict__ vtb) {
    __shared__ bf16 wlds[36864];               // 73728 B: this cg's 12 strips, fragment-order
    __shared__ bf16 xs[2][48][200];            // 2 x 19200 B double buffer
    const int tid = threadIdx.x;
    const int lane = tid & 63;
    const int w = tid >> 6;                    // 0..11 = strip within cg
    const int l15 = lane & 15;
    const int g = lane >> 4;
    const int cg = blockIdx.x;                 // 0=q 1=k 2=v
    const int rowbase = blockIdx.y * 288;

    // stage W slice once: 36864 bf16 = 4608 bf16x8 = 768 thr x 6 (fully coalesced)
    const bf16* wsrc = wtf + (size_t)cg * 36864;
    #pragma unroll
    for (int it = 0; it < 6; ++it) {
        int idx = tid + it * 768;
        bf16x8 v = *reinterpret_cast<const bf16x8*>(wsrc + (size_t)idx * 8);
        *reinterpret_cast<bf16x8*>(&wlds[(size_t)idx * 8]) = v;
    }
    // stage x chunk 0 into xs[0]
    #pragma unroll
    for (int it = 0; it < 3; ++it) {
        int idx = tid + it * 768;
        int r = idx / 48, cp = idx - r * 48;
        f32x4 xa = *reinterpret_cast<const f32x4*>(x + (size_t)(rowbase + r) * 192 + cp * 4);
        bf16x4 v;
        v[0] = (bf16)xa[0]; v[1] = (bf16)xa[1]; v[2] = (bf16)xa[2]; v[3] = (bf16)xa[3];
        *reinterpret_cast<bf16x4*>(&xs[0][r][cp * 4]) = v;
    }
    __syncthreads();

    // W fragments for this wave's strip (24 VGPR; remat-safe: source is LDS)
    bf16x8 aw[6];
    #pragma unroll
    for (int ks = 0; ks < 6; ++ks)
        aw[ks] = *reinterpret_cast<const bf16x8*>(&wlds[(size_t)(w * 6 + ks) * 512 + lane * 8]);

    const float scl = (cg == 0) ? 0.17677669529663687f * LOG2E : 1.0f;
    const int h = w >> 1;                      // head within group
    const int d0 = (w & 1) * 16 + g * 4;       // d within head
    f32x4 bv = *reinterpret_cast<const f32x4*>(bqkv + cg * 192 + w * 16 + g * 4);
    bf16* qkbase = (cg == 0) ? qb : kb;

    int buf = 0;
    for (int c = 0; c < 6; ++c) {
        // prefetch next x chunk into registers (issues before compute -> latency hidden)
        f32x4 xa[3];
        if (c < 5) {
            #pragma unroll
            for (int it = 0; it < 3; ++it) {
                int idx = tid + it * 768;
                int r = idx / 48, cp = idx - r * 48;
                xa[it] = *reinterpret_cast<const f32x4*>(x + (size_t)(rowbase + (c + 1) * 48 + r) * 192 + cp * 4);
            }
        }
        // compute 3 subtiles of current chunk (pure LDS + MFMA)
        #pragma unroll
        for (int sub = 0; sub < 3; ++sub) {
            const int row0 = rowbase + c * 48 + sub * 16;   // 16-aligned, never crosses 144
            f32x4 acc = (f32x4){0.f, 0.f, 0.f, 0.f};
            #pragma unroll
            for (int ks = 0; ks < 6; ++ks) {
                bf16x8 bfr = *reinterpret_cast<const bf16x8*>(&xs[buf][sub * 16 + l15][ks * 32 + g * 8]);
                acc = MFMA16(aw[ks], bfr, acc);
            }
            const int bidx = row0 / 144;
            const int n = row0 - bidx * 144 + l15;
            float v0 = (acc[0] + bv[0]) * scl;
            float v1 = (acc[1] + bv[1]) * scl;
            float v2 = (acc[2] + bv[2]) * scl;
            float v3 = (acc[3] + bv[3]) * scl;
            if (cg == 2) {
                bf16* dst = vtb + ((size_t)(bidx * 6 + h) * 32 + d0) * 144 + n;
                dst[0]   = (bf16)v0;
                dst[144] = (bf16)v1;
                dst[288] = (bf16)v2;
                dst[432] = (bf16)v3;
            } else {
                bf16x4 sv;
                sv[0] = (bf16)v0; sv[1] = (bf16)v1; sv[2] = (bf16)v2; sv[3] = (bf16)v3;
                *reinterpret_cast<bf16x4*>(qkbase + ((size_t)(bidx * 6 + h) * 144 + n) * 32 + d0) = sv;
            }
        }
        // write prefetched chunk to the other buffer
        if (c < 5) {
            #pragma unroll
            for (int it = 0; it < 3; ++it) {
                int idx = tid + it * 768;
                int r = idx / 48, cp = idx - r * 48;
                bf16x4 v;
                v[0] = (bf16)xa[it][0]; v[1] = (bf16)xa[it][1];
                v[2] = (bf16)xa[it][2]; v[3] = (bf16)xa[it][3];
                *reinterpret_cast<bf16x4*>(&xs[buf ^ 1][r][cp * 4]) = v;
            }
            buf ^= 1;
            __syncthreads();   // next buffer ready for all waves
        }
    }
}

// ---------------- windowed attention (R20 exact: 3 waves, LDS-staged K/V, zeroed pads) ----------------
__global__ __launch_bounds__(192, 3) void k_attn(const bf16* __restrict__ qb,
                                                 const bf16* __restrict__ kb,
                                                 const bf16* __restrict__ vtb,
                                                 const float* __restrict__ msw,
                                                 const bf16* __restrict__ bias,
                                                 bf16* __restrict__ ob) {
    __shared__ bf16 ksh[144][40];   // K rows padded 32->40
    __shared__ bf16 vsh[32][160];   // V^T rows padded 144->160; cols [144,160) ZEROED
    __shared__ bf16 pl[48][168];    // P rows; m padded 144->160 zeros
    const int hb = blockIdx.x;
    const int b = hb / 6;
    const int h = hb - b * 6;
    const int t = b & 63;
    const int wm = b % 15;
    const int tid = threadIdx.x;
    const int lane = tid & 63;
    const int wv = tid >> 6;       // 0..2
    const int l15 = lane & 15;
    const int g = lane >> 4;

    const bf16* qp = qb + (size_t)hb * 4608;
    const bf16* kp = kb + (size_t)hb * 4608;
    const bf16* vp = vtb + (size_t)hb * 4608;

    // cooperative staging: K (144x32) and V^T (32x144), coalesced bf16x8
    #pragma unroll
    for (int it = 0; it < 3; ++it) {
        int c = tid + it * 192;                 // 0..575
        int kr = c >> 2, kc = (c & 3) * 8;
        bf16x8 kvv = *reinterpret_cast<const bf16x8*>(kp + (size_t)kr * 32 + kc);
        *reinterpret_cast<bf16x8*>(&ksh[kr][kc]) = kvv;
        int vr = c / 18, vc = (c - vr * 18) * 8;
        bf16x8 vvv = *reinterpret_cast<const bf16x8*>(vp + (size_t)vr * 144 + vc);
        *reinterpret_cast<bf16x8*>(&vsh[vr][vc]) = vvv;
    }
    {
        bf16x8 z;
        #pragma unroll
        for (int i = 0; i < 8; ++i) z[i] = (bf16)0.f;
        if (tid < 64)   // zero V pad cols [144,160): 32 rows x 2 chunks
            *reinterpret_cast<bf16x8*>(&vsh[tid >> 1][144 + (tid & 1) * 8]) = z;
        if (lane < 32)  // zero this wave's P pad cols [144,160)
            *reinterpret_cast<bf16x8*>(&pl[wv * 16 + (lane >> 1)][144 + (lane & 1) * 8]) = z;
    }
    __syncthreads();

    // register fragments from LDS (once per wave, reused across 3 q-tiles)
    bf16x8 kf[9];
    #pragma unroll
    for (int ct = 0; ct < 9; ++ct)
        kf[ct] = *reinterpret_cast<const bf16x8*>(&ksh[ct * 16 + l15][g * 8]);
    bf16x8 vf[10];
    #pragma unroll
    for (int mc = 0; mc < 5; ++mc) {
        vf[mc]     = *reinterpret_cast<const bf16x8*>(&vsh[l15][mc * 32 + g * 8]);
        vf[5 + mc] = *reinterpret_cast<const bf16x8*>(&vsh[16 + l15][mc * 32 + g * 8]);
    }

    const float* mbase = msw + (size_t)wm * 20736 + l15 * 16 + g * 4;
    const bf16* bbase = bias + (size_t)(t * 6 + h) * 20736 + l15 * 16 + g * 4;

    for (int j = 0; j < 3; ++j) {
        const int n = j * 48 + wv * 16 + l15;
        const int nt = j * 3 + wv;

        // ---- S^T = K·Q^T ----
        bf16x8 bq = *reinterpret_cast<const bf16x8*>(qp + (size_t)n * 32 + g * 8);
        f32x4 s[9];
        #pragma unroll
        for (int ct = 0; ct < 9; ++ct) {
            f32x4 z = (f32x4){0.f, 0.f, 0.f, 0.f};
            s[ct] = MFMA16(kf[ct], bq, z);
        }

        // ---- + bias' + mask*log2e (swizzled, coalesced), p = exp2(.) ----
        const bf16* brow = bbase + nt * 2304;
        const float* mrow = mbase + nt * 2304;
        #pragma unroll
        for (int ct = 0; ct < 9; ++ct) {
            bf16x4 bvv = *reinterpret_cast<const bf16x4*>(brow + ct * 256);
            f32x4 mv = *reinterpret_cast<const f32x4*>(mrow + ct * 256);
            #pragma unroll
            for (int r = 0; r < 4; ++r)
                s[ct][r] = exp2f(fmaf(mv[r], LOG2E, s[ct][r] + (float)bvv[r]));
        }

        // ---- tree sum ----
        f32x4 sm4 = s[8];
        #pragma unroll
        for (int ct = 0; ct < 4; ++ct) {
            #pragma unroll
            for (int r = 0; r < 4; ++r)
                sm4[r] += s[ct][r] + s[ct + 4][r];
        }
        float rsum = (sm4[0] + sm4[1]) + (sm4[2] + sm4[3]);
        rsum += __shfl_xor(rsum, 16);
        rsum += __shfl_xor(rsum, 32);
        const float rinv = 1.0f / rsum;

        // unnormalized P -> LDS (wave-local rows)
        #pragma unroll
        for (int ct = 0; ct < 9; ++ct) {
            bf16x4 pv;
            #pragma unroll
            for (int r = 0; r < 4; ++r) pv[r] = (bf16)s[ct][r];
            *reinterpret_cast<bf16x4*>(&pl[wv * 16 + l15][ct * 16 + g * 4]) = pv;
        }
        __asm__ __volatile__("s_waitcnt lgkmcnt(0)" ::: "memory");

        // ---- O^T = V·P^T ----
        f32x4 o0 = (f32x4){0.f, 0.f, 0.f, 0.f};
        f32x4 o1 = (f32x4){0.f, 0.f, 0.f, 0.f};
        #pragma unroll
        for (int mc = 0; mc < 5; ++mc) {
            bf16x8 pa = *reinterpret_cast<const bf16x8*>(&pl[wv * 16 + l15][mc * 32 + g * 8]);
            o0 = MFMA16(vf[mc], pa, o0);
            o1 = MFMA16(vf[5 + mc], pa, o1);
        }
        bf16* op = ob + (size_t)b * 27648 + (size_t)n * 192 + h * 32;
        bf16x4 s0, s1;
        #pragma unroll
        for (int r = 0; r < 4; ++r) { s0[r] = (bf16)(o0[r] * rinv); s1[r] = (bf16)(o1[r] * rinv); }
        *reinterpret_cast<bf16x4*>(op + g * 4)      = s0;
        *reinterpret_cast<bf16x4*>(op + 16 + g * 4) = s1;
    }
}

// ---------------- output projection (R14 form, unchanged) ----------------
__global__ __launch_bounds__(768, 3) void k_out(const bf16* __restrict__ ob,
                                                const bf16* __restrict__ wt,
                                                const float* __restrict__ bout,
                                                float* __restrict__ out) {
    __shared__ bf16 os[96][200];
    __shared__ float ot[16][196];
    const int tid = threadIdx.x;
    const int lane = tid & 63;
    const int w = tid >> 6;
    const int l15 = lane & 15;
    const int g = lane >> 4;
    const int c0 = w * 16;
    const int rowbase = blockIdx.x * 96;

    bf16x8 a[6];
    #pragma unroll
    for (int ks = 0; ks < 6; ++ks)
        a[ks] = *reinterpret_cast<const bf16x8*>(wt + (size_t)(c0 + l15) * 192 + ks * 32 + g * 8);
    f32x4 bv = *reinterpret_cast<const f32x4*>(bout + c0 + g * 4);

    #pragma unroll
    for (int it = 0; it < 3; ++it) {
        int idx = tid + it * 768;
        int r = idx / 24, cp = idx - r * 24;
        bf16x8 v = *reinterpret_cast<const bf16x8*>(ob + (size_t)(rowbase + r) * 192 + cp * 8);
        *reinterpret_cast<bf16x8*>(&os[r][cp * 8]) = v;
    }
    __syncthreads();

    for (int sub = 0; sub < 6; ++sub) {
        bf16x8 bfr[6];
        #pragma unroll
        for (int ks = 0; ks < 6; ++ks)
            bfr[ks] = *reinterpret_cast<const bf16x8*>(&os[sub * 16 + l15][ks * 32 + g * 8]);
        f32x4 acc = (f32x4){0.f, 0.f, 0.f, 0.f};
        #pragma unroll
        for (int ks = 0; ks < 6; ++ks)
            acc = MFMA16(a[ks], bfr[ks], acc);
        __syncthreads();
        f32x4 sv;
        sv[0] = acc[0] + bv[0];
        sv[1] = acc[1] + bv[1];
        sv[2] = acc[2] + bv[2];
        sv[3] = acc[3] + bv[3];
        *reinterpret_cast<f32x4*>(&ot[l15][c0 + g * 4]) = sv;
        __syncthreads();
        int rr = tid / 48, c4 = tid - rr * 48;
        f32x4 vv = *reinterpret_cast<const f32x4*>(&ot[rr][c4 * 4]);
        *reinterpret_cast<f32x4*>(out + (size_t)(rowbase + sub * 16 + rr) * 192 + c4 * 4) = vv;
    }
}

extern "C" void kernel_launch(void* const* d_in, const int* in_sizes, int n_in,
                              void* d_out, int out_size, void* d_ws, size_t ws_size,
                              hipStream_t stream) {
    const float* x    = (const float*)d_in[0];
    const float* mask = (const float*)d_in[1];
    const float* wqkv = (const float*)d_in[2];
    const float* bqkv = (const float*)d_in[3];
    const float* wout = (const float*)d_in[4];
    const float* bout = (const float*)d_in[5];
    const float* btab = (const float*)d_in[6];
    float* out = (float*)d_out;

    char* ws = (char*)d_ws;
    bf16* wqkvt = (bf16*)(ws);
    bf16* woutt = (bf16*)(ws + 221184);
    bf16* bias  = (bf16*)(ws + 294912);
    bf16* obuf  = (bf16*)(ws + 16220160);
    bf16* qb    = (bf16*)(ws + 69304320);
    bf16* kb    = (bf16*)(ws + 122388480);
    bf16* vtb   = (bf16*)(ws + 175472640);  // ends 228556800
    float* msw  = (float*)(ws + 228556800); // ends 229800960 (~219.2 MiB)

    hipLaunchKernelGGL(k_prep, dim3(576),     dim3(256), 0, stream, wqkv, wout, wqkvt, woutt);
    hipLaunchKernelGGL(k_bias, dim3(384),     dim3(256), 0, stream, btab, bias);
    hipLaunchKernelGGL(k_mswz, dim3(135),     dim3(256), 0, stream, mask, msw);
    hipLaunchKernelGGL(k_qkv,  dim3(3, 480),  dim3(768), 0, stream, x, bqkv, wqkvt, qb, kb, vtb);
    hipLaunchKernelGGL(k_attn, dim3(5760),    dim3(192), 0, stream, qb, kb, vtb, msw, bias, obuf);
    hipLaunchKernelGGL(k_out,  dim3(1440),    dim3(768), 0, stream, obuf, woutt, bout, out);
}

// Round 24
// 228.660 us; speedup vs baseline: 1.1728x; 1.1728x over previous
//
#include <hip/hip_runtime.h>
#include <stdint.h>

typedef __bf16 bf16;
typedef __bf16 bf16x4 __attribute__((ext_vector_type(4)));
typedef __bf16 bf16x8 __attribute__((ext_vector_type(8)));
typedef float  f32x4  __attribute__((ext_vector_type(4)));

#define MFMA16(A, B, C) __builtin_amdgcn_mfma_f32_16x16x32_bf16((A), (B), (C), 0, 0, 0)

#define LOG2E 1.4426950408889634f

// B=960 windows, N=144, DIM=192, HEADS=6, hd=32, TYPES=64, n_mask=15
// FINAL configuration (verified best: 230.1us R20, 233.0us R22).
// Session lessons encoded here:
//  - Softmax: no-max exp2 (logits |L|<~6), log2e prefolded into q-scale/bias/mask fma;
//    P unnormalized (<= e^6, bf16-safe); O scaled by 1/rsum in epilogue.
//  - R8/R21: NEVER cap launch_bounds below live-VGPR need (spills -> 100s of MB scratch).
//  - R10: bias/mask materialized SWIZZLED [th][nt][ct][l15][g] -> every wave load is one
//    contiguous 512B/1KB block (the single biggest attn win: latency-bound, not BW).
//  - R11: store-coalescing via LDS NEUTRAL on this problem. R14: W in fragment-order
//    (contiguous 1KB per fragment) -> remat traffic halved, 106->95us.
//  - R12/R13/R15/R16/R17/R21/R23: all other k_qkv structures (pinning, ks-outer,
//    pairing, 32x32 MFMA, small blocks, W-in-LDS) flat or worse -> ~95us is the
//    practical plateau for this shape at HIP source level.
//  - R19: MFMA pad contract: padded operand regions must be ZEROED on BOTH sides
//    (uninitialized LDS NaN x 0 = NaN).
//  - R20: attn = 3 waves/block, K/V cooperatively LDS-staged once (zeroed pads),
//    register fragments reused across 3 q-tiles; swapped QK^T and swapped PV keep
//    softmax lane-local and output stores vectorized.
//
// ws layout (bytes):
//   wqkvt [36][6][64][8] bf16 @ 0        (221184)  (fragment-order, 16x16 strips)
//   woutt [192][192] bf16 @ 221184       (73728)   ends 294912 ([n][k] k-contig)
//   bias_sw [384][20736] bf16 @ 294912   (15925248) ends 16220160
//   obuf  [138240][192] bf16 @ 16220160  (53084160) ends 69304320
//   qb    [960][6][144][32] bf16 @ 69304320  ends 122388480
//   kb    same @ 122388480 ends 175472640
//   vtb   [960][6][32][144] @ 175472640 ends 228556800
//   mask_sw [15][20736] f32 @ 228556800  (1244160) ends 229800960 (~219.2 MiB)

// ---------------- weight transpose + bf16 cast ----------------
__global__ __launch_bounds__(256) void k_prep(const float* __restrict__ wqkv,
                                              const float* __restrict__ wout,
                                              bf16* __restrict__ wqkvt,
                                              bf16* __restrict__ woutt) {
    int i = blockIdx.x * 256 + threadIdx.x;   // 576 blocks
    if (i < 576 * 192) {
        int blk = i >> 9;                     // strip*6 + ks  (0..215)
        int within = i & 511;
        int lane = within >> 3, j = within & 7;
        int strip = blk / 6, ks = blk - strip * 6;
        int col = strip * 16 + (lane & 15);
        int k = ks * 32 + (lane >> 4) * 8 + j;
        wqkvt[i] = (bf16)wqkv[k * 576 + col];
    } else {
        int jj = i - 576 * 192;
        int n = jj / 192, k = jj - n * 192;
        woutt[jj] = (bf16)wout[k * 192 + n];  // [n][k], k-contiguous
    }
}

// ---------------- earth-bias materialization (swizzled, pre-mult log2e) ----------------
__global__ __launch_bounds__(256) void k_bias(const float* __restrict__ btab,
                                              bf16* __restrict__ bias) {
    __shared__ float tb[3312];
    const int th = blockIdx.x;                 // t*6 + h
    for (int i = threadIdx.x; i < 3312; i += 256)
        tb[i] = btab[(size_t)i * 384 + th] * LOG2E;
    __syncthreads();
    bf16* op = bias + (size_t)th * 20736;
    for (int o = threadIdx.x; o < 20736; o += 256) {
        int nt = o / 2304, r1 = o - nt * 2304;
        int ct = r1 / 256,  r2 = r1 - ct * 256;
        int l15 = r2 >> 4,  gr = r2 & 15;
        int n = nt * 16 + l15, m = ct * 16 + gr;
        int zn = n / 72, rn = n - zn * 72, hn = rn / 12, wn = rn - hn * 12;
        int zm = m / 72, rm = m - zm * 72, hm = rm / 12, wm = rm - hm * 12;
        int idx = 828 * (zn + 2 * zm) + 23 * (hn + 6 * hm) + (wn - wm + 11);
        op[o] = (bf16)tb[idx];
    }
}

// ---------------- mask swizzle ----------------
__global__ __launch_bounds__(256) void k_mswz(const float* __restrict__ mask,
                                              float* __restrict__ msw) {
    const int wm = blockIdx.x / 9;
    const int nt = blockIdx.x - wm * 9;
    const int tid = threadIdx.x;
    const int l15 = tid >> 4, gr = tid & 15;
    const float* src = mask + (size_t)wm * 20736 + (size_t)(nt * 16 + l15) * 144 + gr;
    float* dst = msw + (size_t)wm * 20736 + nt * 2304 + tid;
    #pragma unroll
    for (int ct = 0; ct < 9; ++ct)
        dst[ct * 256] = src[ct * 16];
}

// ---------------- QKV projection (R14 exact) ----------------
// grid 1440 (96 rows), 768 thr = 12 waves; wave w owns strips 3w..3w+2 (48 cols).
__global__ __launch_bounds__(768, 3) void k_qkv(const float* __restrict__ x,
                                                const float* __restrict__ bqkv,
                                                const bf16* __restrict__ wtf,
                                                bf16* __restrict__ qb,
                                                bf16* __restrict__ kb,
                                                bf16* __restrict__ vtb) {
    __shared__ bf16 xs[96][200];               // 38400 B
    const int tid = threadIdx.x;
    const int lane = tid & 63;
    const int w = tid >> 6;
    const int l15 = lane & 15;
    const int g = lane >> 4;
    const int c0 = w * 48;
    const int rowbase = blockIdx.x * 96;

    int hs[3], d0s[3], cgs[3];
    float scl[3];
    f32x4 bv[3];
    #pragma unroll
    for (int s = 0; s < 3; ++s) {
        int cbase = c0 + s * 16;
        int cg = cbase / 192;
        int rem = cbase - cg * 192;
        cgs[s] = cg;
        scl[s] = (cg == 0) ? 0.17677669529663687f * LOG2E : 1.0f;
        hs[s] = rem >> 5;
        d0s[s] = (rem & 31) + g * 4;
        bv[s] = *reinterpret_cast<const f32x4*>(bqkv + cbase + g * 4);
    }

    #pragma unroll
    for (int it = 0; it < 6; ++it) {
        int idx = tid + it * 768;
        int r = idx / 48, cp = idx - r * 48;
        f32x4 xa = *reinterpret_cast<const f32x4*>(x + (size_t)(rowbase + r) * 192 + cp * 4);
        bf16x4 v;
        v[0] = (bf16)xa[0]; v[1] = (bf16)xa[1]; v[2] = (bf16)xa[2]; v[3] = (bf16)xa[3];
        *reinterpret_cast<bf16x4*>(&xs[r][cp * 4]) = v;
    }
    __syncthreads();

    for (int sub = 0; sub < 6; ++sub) {
        const int row0 = rowbase + sub * 16;
        bf16x8 bfr[6];
        #pragma unroll
        for (int ks = 0; ks < 6; ++ks)
            bfr[ks] = *reinterpret_cast<const bf16x8*>(&xs[sub * 16 + l15][ks * 32 + g * 8]);
        f32x4 acc[3];
        #pragma unroll
        for (int s = 0; s < 3; ++s) acc[s] = (f32x4){0.f, 0.f, 0.f, 0.f};
        #pragma unroll
        for (int ks = 0; ks < 6; ++ks) {
            #pragma unroll
            for (int s = 0; s < 3; ++s) {
                bf16x8 aw = *reinterpret_cast<const bf16x8*>(wtf + (size_t)(((w * 3 + s) * 6 + ks) * 512 + lane * 8));
                acc[s] = MFMA16(aw, bfr[ks], acc[s]);
            }
        }
        const int bidx = row0 / 144;
        const int n = row0 - bidx * 144 + l15;
        #pragma unroll
        for (int s = 0; s < 3; ++s) {
            float v0 = (acc[s][0] + bv[s][0]) * scl[s];
            float v1 = (acc[s][1] + bv[s][1]) * scl[s];
            float v2 = (acc[s][2] + bv[s][2]) * scl[s];
            float v3 = (acc[s][3] + bv[s][3]) * scl[s];
            if (cgs[s] == 2) {
                bf16* dst = vtb + ((size_t)(bidx * 6 + hs[s]) * 32 + d0s[s]) * 144 + n;
                dst[0]   = (bf16)v0;
                dst[144] = (bf16)v1;
                dst[288] = (bf16)v2;
                dst[432] = (bf16)v3;
            } else {
                bf16x4 sv;
                sv[0] = (bf16)v0; sv[1] = (bf16)v1; sv[2] = (bf16)v2; sv[3] = (bf16)v3;
                bf16* base = (cgs[s] == 0) ? qb : kb;
                *reinterpret_cast<bf16x4*>(base + ((size_t)(bidx * 6 + hs[s]) * 144 + n) * 32 + d0s[s]) = sv;
            }
        }
    }
}

// ---------------- windowed attention (R20 exact: 3 waves, LDS-staged K/V, zeroed pads) ----------------
__global__ __launch_bounds__(192, 3) void k_attn(const bf16* __restrict__ qb,
                                                 const bf16* __restrict__ kb,
                                                 const bf16* __restrict__ vtb,
                                                 const float* __restrict__ msw,
                                                 const bf16* __restrict__ bias,
                                                 bf16* __restrict__ ob) {
    __shared__ bf16 ksh[144][40];   // K rows padded 32->40
    __shared__ bf16 vsh[32][160];   // V^T rows padded 144->160; cols [144,160) ZEROED
    __shared__ bf16 pl[48][168];    // P rows; m padded 144->160 zeros
    const int hb = blockIdx.x;
    const int b = hb / 6;
    const int h = hb - b * 6;
    const int t = b & 63;
    const int wm = b % 15;
    const int tid = threadIdx.x;
    const int lane = tid & 63;
    const int wv = tid >> 6;       // 0..2
    const int l15 = lane & 15;
    const int g = lane >> 4;

    const bf16* qp = qb + (size_t)hb * 4608;
    const bf16* kp = kb + (size_t)hb * 4608;
    const bf16* vp = vtb + (size_t)hb * 4608;

    // cooperative staging: K (144x32) and V^T (32x144), coalesced bf16x8
    #pragma unroll
    for (int it = 0; it < 3; ++it) {
        int c = tid + it * 192;                 // 0..575
        int kr = c >> 2, kc = (c & 3) * 8;
        bf16x8 kvv = *reinterpret_cast<const bf16x8*>(kp + (size_t)kr * 32 + kc);
        *reinterpret_cast<bf16x8*>(&ksh[kr][kc]) = kvv;
        int vr = c / 18, vc = (c - vr * 18) * 8;
        bf16x8 vvv = *reinterpret_cast<const bf16x8*>(vp + (size_t)vr * 144 + vc);
        *reinterpret_cast<bf16x8*>(&vsh[vr][vc]) = vvv;
    }
    {
        bf16x8 z;
        #pragma unroll
        for (int i = 0; i < 8; ++i) z[i] = (bf16)0.f;
        if (tid < 64)   // zero V pad cols [144,160): 32 rows x 2 chunks
            *reinterpret_cast<bf16x8*>(&vsh[tid >> 1][144 + (tid & 1) * 8]) = z;
        if (lane < 32)  // zero this wave's P pad cols [144,160)
            *reinterpret_cast<bf16x8*>(&pl[wv * 16 + (lane >> 1)][144 + (lane & 1) * 8]) = z;
    }
    __syncthreads();

    // register fragments from LDS (once per wave, reused across 3 q-tiles)
    bf16x8 kf[9];
    #pragma unroll
    for (int ct = 0; ct < 9; ++ct)
        kf[ct] = *reinterpret_cast<const bf16x8*>(&ksh[ct * 16 + l15][g * 8]);
    bf16x8 vf[10];
    #pragma unroll
    for (int mc = 0; mc < 5; ++mc) {
        vf[mc]     = *reinterpret_cast<const bf16x8*>(&vsh[l15][mc * 32 + g * 8]);
        vf[5 + mc] = *reinterpret_cast<const bf16x8*>(&vsh[16 + l15][mc * 32 + g * 8]);
    }

    const float* mbase = msw + (size_t)wm * 20736 + l15 * 16 + g * 4;
    const bf16* bbase = bias + (size_t)(t * 6 + h) * 20736 + l15 * 16 + g * 4;

    for (int j = 0; j < 3; ++j) {
        const int n = j * 48 + wv * 16 + l15;
        const int nt = j * 3 + wv;

        // ---- S^T = K·Q^T ----
        bf16x8 bq = *reinterpret_cast<const bf16x8*>(qp + (size_t)n * 32 + g * 8);
        f32x4 s[9];
        #pragma unroll
        for (int ct = 0; ct < 9; ++ct) {
            f32x4 z = (f32x4){0.f, 0.f, 0.f, 0.f};
            s[ct] = MFMA16(kf[ct], bq, z);
        }

        // ---- + bias' + mask*log2e (swizzled, coalesced), p = exp2(.) ----
        const bf16* brow = bbase + nt * 2304;
        const float* mrow = mbase + nt * 2304;
        #pragma unroll
        for (int ct = 0; ct < 9; ++ct) {
            bf16x4 bvv = *reinterpret_cast<const bf16x4*>(brow + ct * 256);
            f32x4 mv = *reinterpret_cast<const f32x4*>(mrow + ct * 256);
            #pragma unroll
            for (int r = 0; r < 4; ++r)
                s[ct][r] = exp2f(fmaf(mv[r], LOG2E, s[ct][r] + (float)bvv[r]));
        }

        // ---- tree sum ----
        f32x4 sm4 = s[8];
        #pragma unroll
        for (int ct = 0; ct < 4; ++ct) {
            #pragma unroll
            for (int r = 0; r < 4; ++r)
                sm4[r] += s[ct][r] + s[ct + 4][r];
        }
        float rsum = (sm4[0] + sm4[1]) + (sm4[2] + sm4[3]);
        rsum += __shfl_xor(rsum, 16);
        rsum += __shfl_xor(rsum, 32);
        const float rinv = 1.0f / rsum;

        // unnormalized P -> LDS (wave-local rows)
        #pragma unroll
        for (int ct = 0; ct < 9; ++ct) {
            bf16x4 pv;
            #pragma unroll
            for (int r = 0; r < 4; ++r) pv[r] = (bf16)s[ct][r];
            *reinterpret_cast<bf16x4*>(&pl[wv * 16 + l15][ct * 16 + g * 4]) = pv;
        }
        __asm__ __volatile__("s_waitcnt lgkmcnt(0)" ::: "memory");

        // ---- O^T = V·P^T ----
        f32x4 o0 = (f32x4){0.f, 0.f, 0.f, 0.f};
        f32x4 o1 = (f32x4){0.f, 0.f, 0.f, 0.f};
        #pragma unroll
        for (int mc = 0; mc < 5; ++mc) {
            bf16x8 pa = *reinterpret_cast<const bf16x8*>(&pl[wv * 16 + l15][mc * 32 + g * 8]);
            o0 = MFMA16(vf[mc], pa, o0);
            o1 = MFMA16(vf[5 + mc], pa, o1);
        }
        bf16* op = ob + (size_t)b * 27648 + (size_t)n * 192 + h * 32;
        bf16x4 s0, s1;
        #pragma unroll
        for (int r = 0; r < 4; ++r) { s0[r] = (bf16)(o0[r] * rinv); s1[r] = (bf16)(o1[r] * rinv); }
        *reinterpret_cast<bf16x4*>(op + g * 4)      = s0;
        *reinterpret_cast<bf16x4*>(op + 16 + g * 4) = s1;
    }
}

// ---------------- output projection (R14 form, unchanged) ----------------
__global__ __launch_bounds__(768, 3) void k_out(const bf16* __restrict__ ob,
                                                const bf16* __restrict__ wt,
                                                const float* __restrict__ bout,
                                                float* __restrict__ out) {
    __shared__ bf16 os[96][200];
    __shared__ float ot[16][196];
    const int tid = threadIdx.x;
    const int lane = tid & 63;
    const int w = tid >> 6;
    const int l15 = lane & 15;
    const int g = lane >> 4;
    const int c0 = w * 16;
    const int rowbase = blockIdx.x * 96;

    bf16x8 a[6];
    #pragma unroll
    for (int ks = 0; ks < 6; ++ks)
        a[ks] = *reinterpret_cast<const bf16x8*>(wt + (size_t)(c0 + l15) * 192 + ks * 32 + g * 8);
    f32x4 bv = *reinterpret_cast<const f32x4*>(bout + c0 + g * 4);

    #pragma unroll
    for (int it = 0; it < 3; ++it) {
        int idx = tid + it * 768;
        int r = idx / 24, cp = idx - r * 24;
        bf16x8 v = *reinterpret_cast<const bf16x8*>(ob + (size_t)(rowbase + r) * 192 + cp * 8);
        *reinterpret_cast<bf16x8*>(&os[r][cp * 8]) = v;
    }
    __syncthreads();

    for (int sub = 0; sub < 6; ++sub) {
        bf16x8 bfr[6];
        #pragma unroll
        for (int ks = 0; ks < 6; ++ks)
            bfr[ks] = *reinterpret_cast<const bf16x8*>(&os[sub * 16 + l15][ks * 32 + g * 8]);
        f32x4 acc = (f32x4){0.f, 0.f, 0.f, 0.f};
        #pragma unroll
        for (int ks = 0; ks < 6; ++ks)
            acc = MFMA16(a[ks], bfr[ks], acc);
        __syncthreads();
        f32x4 sv;
        sv[0] = acc[0] + bv[0];
        sv[1] = acc[1] + bv[1];
        sv[2] = acc[2] + bv[2];
        sv[3] = acc[3] + bv[3];
        *reinterpret_cast<f32x4*>(&ot[l15][c0 + g * 4]) = sv;
        __syncthreads();
        int rr = tid / 48, c4 = tid - rr * 48;
        f32x4 vv = *reinterpret_cast<const f32x4*>(&ot[rr][c4 * 4]);
        *reinterpret_cast<f32x4*>(out + (size_t)(rowbase + sub * 16 + rr) * 192 + c4 * 4) = vv;
    }
}

extern "C" void kernel_launch(void* const* d_in, const int* in_sizes, int n_in,
                              void* d_out, int out_size, void* d_ws, size_t ws_size,
                              hipStream_t stream) {
    const float* x    = (const float*)d_in[0];
    const float* mask = (const float*)d_in[1];
    const float* wqkv = (const float*)d_in[2];
    const float* bqkv = (const float*)d_in[3];
    const float* wout = (const float*)d_in[4];
    const float* bout = (const float*)d_in[5];
    const float* btab = (const float*)d_in[6];
    float* out = (float*)d_out;

    char* ws = (char*)d_ws;
    bf16* wqkvt = (bf16*)(ws);
    bf16* woutt = (bf16*)(ws + 221184);
    bf16* bias  = (bf16*)(ws + 294912);
    bf16* obuf  = (bf16*)(ws + 16220160);
    bf16* qb    = (bf16*)(ws + 69304320);
    bf16* kb    = (bf16*)(ws + 122388480);
    bf16* vtb   = (bf16*)(ws + 175472640);  // ends 228556800
    float* msw  = (float*)(ws + 228556800); // ends 229800960 (~219.2 MiB)

    hipLaunchKernelGGL(k_prep, dim3(576),  dim3(256), 0, stream, wqkv, wout, wqkvt, woutt);
    hipLaunchKernelGGL(k_bias, dim3(384),  dim3(256), 0, stream, btab, bias);
    hipLaunchKernelGGL(k_mswz, dim3(135),  dim3(256), 0, stream, mask, msw);
    hipLaunchKernelGGL(k_qkv,  dim3(1440), dim3(768), 0, stream, x, bqkv, wqkvt, qb, kb, vtb);
    hipLaunchKernelGGL(k_attn, dim3(5760), dim3(192), 0, stream, qb, kb, vtb, msw, bias, obuf);
    hipLaunchKernelGGL(k_out,  dim3(1440), dim3(768), 0, stream, obuf, woutt, bout, out);
}